// Round 3
// baseline (754.439 us; speedup 1.0000x reference)
//
#include <hip/hip_runtime.h>

#define D_IN_C 16
#define D_OUT_C 32
#define NB_LOG 6                 // 64 nodes per bucket
#define NB (1 << NB_LOG)         // 64
#define NB_MASK (NB - 1)

// ---------------------------------------------------------------------------
// K1: h = relu(x@w1+b1)@w2+b2 ; zero bucket counters (new path) or
// summed/cnt (fallback path).
// ---------------------------------------------------------------------------
__global__ __launch_bounds__(256) void mlp_kernel(
    const float* __restrict__ x,
    const float* __restrict__ w1, const float* __restrict__ b1,
    const float* __restrict__ w2, const float* __restrict__ b2,
    float* __restrict__ h, float* __restrict__ summed, int* __restrict__ cnt,
    int* __restrict__ countPad, int pad_ints, int n_nodes) {
  __shared__ float sw1[256];
  __shared__ float sw2[256];
  __shared__ float sb1[16];
  __shared__ float sb2[16];
  int t = threadIdx.x;
  sw1[t] = w1[t];
  sw2[t] = w2[t];
  if (t < 16) { sb1[t] = b1[t]; sb2[t] = b2[t]; }
  __syncthreads();

  int n = blockIdx.x * blockDim.x + t;

  if (countPad && n < pad_ints) countPad[n] = 0;
  if (n >= n_nodes) return;

  float xi[16];
  const float4* xr = (const float4*)(x + (size_t)n * 16);
  float4 v0 = xr[0], v1 = xr[1], v2 = xr[2], v3 = xr[3];
  xi[0]=v0.x; xi[1]=v0.y; xi[2]=v0.z; xi[3]=v0.w;
  xi[4]=v1.x; xi[5]=v1.y; xi[6]=v1.z; xi[7]=v1.w;
  xi[8]=v2.x; xi[9]=v2.y; xi[10]=v2.z; xi[11]=v2.w;
  xi[12]=v3.x; xi[13]=v3.y; xi[14]=v3.z; xi[15]=v3.w;

  float t1[16];
#pragma unroll
  for (int j = 0; j < 16; ++j) {
    float acc = sb1[j];
#pragma unroll
    for (int k = 0; k < 16; ++k) acc += xi[k] * sw1[k * 16 + j];
    t1[j] = fmaxf(acc, 0.0f);
  }
  float hh[16];
#pragma unroll
  for (int j = 0; j < 16; ++j) {
    float acc = sb2[j];
#pragma unroll
    for (int k = 0; k < 16; ++k) acc += t1[k] * sw2[k * 16 + j];
    hh[j] = acc;
  }

  float4* hw = (float4*)(h + (size_t)n * 16);
  hw[0] = make_float4(hh[0], hh[1], hh[2], hh[3]);
  hw[1] = make_float4(hh[4], hh[5], hh[6], hh[7]);
  hw[2] = make_float4(hh[8], hh[9], hh[10], hh[11]);
  hw[3] = make_float4(hh[12], hh[13], hh[14], hh[15]);

  if (cnt) cnt[n] = 0;
  if (summed) {
    float4* sz = (float4*)(summed + (size_t)n * 16);
    float4 z = make_float4(0.f, 0.f, 0.f, 0.f);
    sz[0] = z; sz[1] = z; sz[2] = z; sz[3] = z;
  }
}

// ---------------------------------------------------------------------------
// K2: per-bucket histogram. Counters padded to one 64B line each to keep
// same-line serialization bounded at edges/bucket (~2048).
// ---------------------------------------------------------------------------
__global__ __launch_bounds__(256) void hist_kernel(
    const int* __restrict__ dst, int* __restrict__ countPad, int n_edges) {
  int e = blockIdx.x * 256 + threadIdx.x;
  if (e < n_edges) atomicAdd(&countPad[(dst[e] >> NB_LOG) * 16], 1);
}

// ---------------------------------------------------------------------------
// K3: single-block exclusive scan of bucket counts -> base[], cursorPad[].
// ---------------------------------------------------------------------------
__global__ __launch_bounds__(256) void scan_kernel(
    const int* __restrict__ countPad, int* __restrict__ base,
    int* __restrict__ cursorPad, int nbuck) {
  __shared__ int ps[256];
  int t = threadIdx.x;
  int per = (nbuck + 255) / 256;
  int beg = t * per;
  int end = beg + per; if (end > nbuck) end = nbuck;
  int sum = 0;
  for (int i = beg; i < end; ++i) sum += countPad[i * 16];
  ps[t] = sum;
  __syncthreads();
#pragma unroll
  for (int off = 1; off < 256; off <<= 1) {
    int add = (t >= off) ? ps[t - off] : 0;
    __syncthreads();
    ps[t] += add;
    __syncthreads();
  }
  int run = ps[t] - sum;  // exclusive prefix
  for (int i = beg; i < end; ++i) {
    base[i] = run;
    cursorPad[i * 16] = run;
    run += countPad[i * 16];
  }
  if (t == 255) base[nbuck] = ps[255];
}

// ---------------------------------------------------------------------------
// K4: bin edges into coarse buckets. 1563 sequentially-advancing write heads
// -> L2 lines fill completely (vs 100K random heads = 16x write blowup).
// pack = (src << 6) | (dst & 63)   (src < 2^17, fits easily)
// ---------------------------------------------------------------------------
__global__ __launch_bounds__(256) void bin_kernel(
    const int* __restrict__ src, const int* __restrict__ dst,
    int* __restrict__ cursorPad, unsigned int* __restrict__ ebuf, int n_edges) {
  int e = blockIdx.x * 256 + threadIdx.x;
  if (e >= n_edges) return;
  int d = dst[e];
  int b = d >> NB_LOG;
  int p = atomicAdd(&cursorPad[b * 16], 1);
  ebuf[p] = ((unsigned int)src[e] << NB_LOG) | (unsigned int)(d & NB_MASK);
}

// ---------------------------------------------------------------------------
// K5: per-bucket aggregate into LDS (no global f32 atomics) + fused SAGE
// epilogue. One block per bucket of 64 nodes.
// ---------------------------------------------------------------------------
__global__ __launch_bounds__(256) void agg_out_kernel(
    const float* __restrict__ h, const unsigned int* __restrict__ ebuf,
    const int* __restrict__ base,
    const float* __restrict__ wl, const float* __restrict__ bl,
    const float* __restrict__ wr, float* __restrict__ out, int n_nodes) {
  __shared__ float ssum[NB * 16];   // 4 KB
  __shared__ int   scnt[NB];
  __shared__ float swl[512];
  __shared__ float swr[512];
  __shared__ float sbl[32];

  int t = threadIdx.x;
  int b = blockIdx.x;

  for (int i = t; i < 512; i += 256) { swl[i] = wl[i]; swr[i] = wr[i]; }
  if (t < 32) sbl[t] = bl[t];
#pragma unroll
  for (int i = t; i < NB * 16; i += 256) ssum[i] = 0.0f;
  if (t < NB) scnt[t] = 0;
  __syncthreads();

  int beg = base[b];
  int end = base[b + 1];

  int g = t >> 4;        // 16 groups of 16 lanes
  int k = t & 15;

  for (int p = beg + g * 16; p < end; p += 256) {
    int m = end - p; if (m > 16) m = 16;
    unsigned int ev = (k < m) ? ebuf[p + k] : 0u;
    if (m == 16) {
#pragma unroll
      for (int kk = 0; kk < 16; ++kk) {
        unsigned int e2 = __shfl(ev, kk, 16);
        int s  = (int)(e2 >> NB_LOG);
        int dl = (int)(e2 & NB_MASK);
        atomicAdd(&ssum[dl * 16 + k], h[(size_t)s * 16 + k]);
        if (k == 0) atomicAdd(&scnt[dl], 1);
      }
    } else {
      for (int kk = 0; kk < m; ++kk) {
        unsigned int e2 = __shfl(ev, kk, 16);
        int s  = (int)(e2 >> NB_LOG);
        int dl = (int)(e2 & NB_MASK);
        atomicAdd(&ssum[dl * 16 + k], h[(size_t)s * 16 + k]);
        if (k == 0) atomicAdd(&scnt[dl], 1);
      }
    }
  }
  __syncthreads();

  // epilogue: out = mean @ wl + bl + h @ wr for the 64 nodes of this bucket
  int j = t & 31;
  for (int nl = t >> 5; nl < NB; nl += 8) {
    int n = b * NB + nl;
    if (n >= n_nodes) break;
    float inv = 1.0f / fmaxf((float)scnt[nl], 1.0f);
    float acc = sbl[j];
    const float* hr = h + (size_t)n * 16;
#pragma unroll
    for (int kk = 0; kk < 16; ++kk) {
      float mv = ssum[nl * 16 + kk] * inv;
      acc += mv * swl[kk * 32 + j] + hr[kk] * swr[kk * 32 + j];
    }
    out[(size_t)n * 32 + j] = acc;
  }
}

// ---------------------------------------------------------------------------
// FALLBACK PATH (verified atomic kernels) — used only if ws too small.
// ---------------------------------------------------------------------------
__global__ __launch_bounds__(256) void scatter_kernel(
    const int* __restrict__ src, const int* __restrict__ dst,
    const float* __restrict__ h, float* __restrict__ summed,
    int* __restrict__ cnt, long long n_edges) {
  long long tid = (long long)blockIdx.x * blockDim.x + threadIdx.x;
  long long e = tid >> 4;
  int k = (int)(tid & 15);
  if (e >= n_edges) return;
  int s = src[e];
  int d = dst[e];
  float val = h[(size_t)s * 16 + k];
  atomicAdd(&summed[(size_t)d * 16 + k], val);
  if (k == 0) atomicAdd(&cnt[d], 1);
}

__global__ __launch_bounds__(256) void out_kernel(
    const float* __restrict__ h, const float* __restrict__ summed,
    const int* __restrict__ cnt,
    const float* __restrict__ wl, const float* __restrict__ bl,
    const float* __restrict__ wr, float* __restrict__ out, int n_nodes) {
  __shared__ float swl[512];
  __shared__ float swr[512];
  __shared__ float sbl[32];
  int t = threadIdx.x;
  for (int i = t; i < 512; i += 256) { swl[i] = wl[i]; swr[i] = wr[i]; }
  if (t < 32) sbl[t] = bl[t];
  __syncthreads();

  int gid = blockIdx.x * 256 + t;
  int n = gid >> 5;
  int j = gid & 31;
  if (n >= n_nodes) return;

  float inv = 1.0f / fmaxf((float)cnt[n], 1.0f);
  const float* hr = h + (size_t)n * 16;
  const float* sr = summed + (size_t)n * 16;
  float acc = sbl[j];
#pragma unroll
  for (int k = 0; k < 16; ++k) {
    acc += sr[k] * inv * swl[k * 32 + j] + hr[k] * swr[k * 32 + j];
  }
  out[(size_t)n * 32 + j] = acc;
}

// ---------------------------------------------------------------------------
extern "C" void kernel_launch(void* const* d_in, const int* in_sizes, int n_in,
                              void* d_out, int out_size, void* d_ws, size_t ws_size,
                              hipStream_t stream) {
  const float* x  = (const float*)d_in[0];
  const int* eidx = (const int*)d_in[1];
  const float* w1 = (const float*)d_in[2];
  const float* b1 = (const float*)d_in[3];
  const float* w2 = (const float*)d_in[4];
  const float* b2 = (const float*)d_in[5];
  const float* wl = (const float*)d_in[6];
  const float* bl = (const float*)d_in[7];
  const float* wr = (const float*)d_in[8];
  float* out = (float*)d_out;

  const int n_nodes = in_sizes[0] / D_IN_C;             // 100000
  const long long n_edges = (long long)in_sizes[1] / 2; // 3200000
  const int* src = eidx;
  const int* dst = eidx + n_edges;

  const int node_blocks = (n_nodes + 255) / 256;         // 391
  const int edge_blocks = (int)((n_edges + 255) / 256);  // 12500
  const int nbuck = (n_nodes + NB - 1) / NB;             // 1563
  const int pad_ints = nbuck * 16;

  // New-path workspace layout.
  float*        h         = (float*)d_ws;                     // N*16 f32
  int*          countPad  = (int*)(h + (size_t)n_nodes * 16); // nbuck*16
  int*          cursorPad = countPad + pad_ints;              // nbuck*16
  int*          base      = cursorPad + pad_ints;             // nbuck+1
  unsigned int* ebuf      = (unsigned int*)(base + nbuck + 1);// E u32

  size_t need = ((size_t)n_nodes * 16 + 2ull * pad_ints + (nbuck + 1)
                 + (size_t)n_edges) * 4;

  if (ws_size >= need) {
    // ---- coarse-bucket counting sort + LDS aggregation ----
    mlp_kernel<<<node_blocks, 256, 0, stream>>>(
        x, w1, b1, w2, b2, h, nullptr, nullptr, countPad, pad_ints, n_nodes);
    hist_kernel<<<edge_blocks, 256, 0, stream>>>(dst, countPad, (int)n_edges);
    scan_kernel<<<1, 256, 0, stream>>>(countPad, base, cursorPad, nbuck);
    bin_kernel<<<edge_blocks, 256, 0, stream>>>(src, dst, cursorPad, ebuf,
                                                (int)n_edges);
    agg_out_kernel<<<nbuck, 256, 0, stream>>>(h, ebuf, base, wl, bl, wr, out,
                                              n_nodes);
  } else {
    // ---- fallback: verified atomic path ----
    float* summed = h + (size_t)n_nodes * 16;
    int*   fcnt   = (int*)(summed + (size_t)n_nodes * 16);
    mlp_kernel<<<node_blocks, 256, 0, stream>>>(
        x, w1, b1, w2, b2, h, summed, fcnt, nullptr, 0, n_nodes);
    {
      long long total = n_edges * 16;
      int blocks = (int)((total + 255) / 256);
      scatter_kernel<<<blocks, 256, 0, stream>>>(src, dst, h, summed, fcnt, n_edges);
    }
    {
      long long total = (long long)n_nodes * 32;
      int blocks = (int)((total + 255) / 256);
      out_kernel<<<blocks, 256, 0, stream>>>(h, summed, fcnt, wl, bl, wr, out, n_nodes);
    }
  }
}

// Round 4
// 517.445 us; speedup vs baseline: 1.4580x; 1.4580x over previous
//
#include <hip/hip_runtime.h>

#define D_IN_C 16
#define D_OUT_C 32
#define NB_LOG 6                 // 64 nodes per bucket
#define NB (1 << NB_LOG)         // 64
#define NB_MASK (NB - 1)
#define MAXBUCK 1600             // supports up to 102400 nodes
#define EPB 12800                // edges per block in hist/bin (50*256)

// ---------------------------------------------------------------------------
// K1: h = relu(x@w1+b1)@w2+b2 ; zero bucket counts (new path) or
// summed/cnt (fallback path).
// ---------------------------------------------------------------------------
__global__ __launch_bounds__(256) void mlp_kernel(
    const float* __restrict__ x,
    const float* __restrict__ w1, const float* __restrict__ b1,
    const float* __restrict__ w2, const float* __restrict__ b2,
    float* __restrict__ h, float* __restrict__ summed, int* __restrict__ cnt,
    int* __restrict__ gcount, int nbuck, int n_nodes) {
  __shared__ float sw1[256];
  __shared__ float sw2[256];
  __shared__ float sb1[16];
  __shared__ float sb2[16];
  int t = threadIdx.x;
  sw1[t] = w1[t];
  sw2[t] = w2[t];
  if (t < 16) { sb1[t] = b1[t]; sb2[t] = b2[t]; }
  __syncthreads();

  int n = blockIdx.x * blockDim.x + t;

  if (gcount && n < nbuck) gcount[n] = 0;
  if (n >= n_nodes) return;

  float xi[16];
  const float4* xr = (const float4*)(x + (size_t)n * 16);
  float4 v0 = xr[0], v1 = xr[1], v2 = xr[2], v3 = xr[3];
  xi[0]=v0.x; xi[1]=v0.y; xi[2]=v0.z; xi[3]=v0.w;
  xi[4]=v1.x; xi[5]=v1.y; xi[6]=v1.z; xi[7]=v1.w;
  xi[8]=v2.x; xi[9]=v2.y; xi[10]=v2.z; xi[11]=v2.w;
  xi[12]=v3.x; xi[13]=v3.y; xi[14]=v3.z; xi[15]=v3.w;

  float t1[16];
#pragma unroll
  for (int j = 0; j < 16; ++j) {
    float acc = sb1[j];
#pragma unroll
    for (int k = 0; k < 16; ++k) acc += xi[k] * sw1[k * 16 + j];
    t1[j] = fmaxf(acc, 0.0f);
  }
  float hh[16];
#pragma unroll
  for (int j = 0; j < 16; ++j) {
    float acc = sb2[j];
#pragma unroll
    for (int k = 0; k < 16; ++k) acc += t1[k] * sw2[k * 16 + j];
    hh[j] = acc;
  }

  float4* hw = (float4*)(h + (size_t)n * 16);
  hw[0] = make_float4(hh[0], hh[1], hh[2], hh[3]);
  hw[1] = make_float4(hh[4], hh[5], hh[6], hh[7]);
  hw[2] = make_float4(hh[8], hh[9], hh[10], hh[11]);
  hw[3] = make_float4(hh[12], hh[13], hh[14], hh[15]);

  if (cnt) cnt[n] = 0;
  if (summed) {
    float4* sz = (float4*)(summed + (size_t)n * 16);
    float4 z = make_float4(0.f, 0.f, 0.f, 0.f);
    sz[0] = z; sz[1] = z; sz[2] = z; sz[3] = z;
  }
}

// ---------------------------------------------------------------------------
// K2: per-bucket histogram, LDS-aggregated per block (EPB edges/block).
// Global atomics: ~nbuck per block (vs 1 per edge) -> ~390K total.
// ---------------------------------------------------------------------------
__global__ __launch_bounds__(256) void hist_kernel(
    const int* __restrict__ dst, int* __restrict__ gcount,
    int nbuck, int n_edges) {
  __shared__ int lcnt[MAXBUCK];
  int t = threadIdx.x;
  for (int i = t; i < MAXBUCK; i += 256) lcnt[i] = 0;
  __syncthreads();
  int e0 = blockIdx.x * EPB;
  int e1 = e0 + EPB; if (e1 > n_edges) e1 = n_edges;
  for (int e = e0 + t; e < e1; e += 256)
    atomicAdd(&lcnt[dst[e] >> NB_LOG], 1);
  __syncthreads();
  for (int b = t; b < nbuck; b += 256) {
    int c = lcnt[b];
    if (c) atomicAdd(&gcount[b], c);
  }
}

// ---------------------------------------------------------------------------
// K3: single-block exclusive scan over nbuck bucket counts.
// Writes base[0..nbuck] (sentinel at nbuck) and cursor[] = base[].
// ---------------------------------------------------------------------------
__global__ __launch_bounds__(256) void scan_kernel(
    const int* __restrict__ gcount, int* __restrict__ base,
    int* __restrict__ cursor, int nbuck) {
  __shared__ int ps[256];
  int t = threadIdx.x;
  int per = (nbuck + 255) / 256;
  int beg = t * per;
  int end = beg + per; if (end > nbuck) end = nbuck;
  int sum = 0;
  for (int i = beg; i < end; ++i) sum += gcount[i];
  ps[t] = sum;
  __syncthreads();
#pragma unroll
  for (int off = 1; off < 256; off <<= 1) {
    int add = (t >= off) ? ps[t - off] : 0;
    __syncthreads();
    ps[t] += add;
    __syncthreads();
  }
  int run = ps[t] - sum;  // exclusive prefix
  for (int i = beg; i < end; ++i) {
    base[i] = run;
    cursor[i] = run;
    run += gcount[i];
  }
  if (t == 255) base[nbuck] = ps[255];
}

// ---------------------------------------------------------------------------
// K4: bin edges. Per block: LDS count -> span reservation (1 atomic-with-
// return per (block,bucket)) -> LDS-rank scatter. Writes are runs of ~8
// consecutive entries per span -> minimal partial-line amplification.
// pack = (src << 6) | (dst & 63)
// ---------------------------------------------------------------------------
__global__ __launch_bounds__(256) void bin_kernel(
    const int* __restrict__ src, const int* __restrict__ dst,
    int* __restrict__ cursor, unsigned int* __restrict__ ebuf,
    int nbuck, int n_edges) {
  __shared__ int lcnt[MAXBUCK];
  __shared__ int lspan[MAXBUCK];
  int t = threadIdx.x;
  for (int i = t; i < MAXBUCK; i += 256) lcnt[i] = 0;
  __syncthreads();
  int e0 = blockIdx.x * EPB;
  int e1 = e0 + EPB; if (e1 > n_edges) e1 = n_edges;
  // phase A: local count
  for (int e = e0 + t; e < e1; e += 256)
    atomicAdd(&lcnt[dst[e] >> NB_LOG], 1);
  __syncthreads();
  // phase B: reserve spans, reset counters for rank pass
  for (int b = t; b < nbuck; b += 256) {
    int c = lcnt[b];
    lspan[b] = c ? atomicAdd(&cursor[b], c) : 0;
    lcnt[b] = 0;
  }
  __syncthreads();
  // phase C: scatter
  for (int e = e0 + t; e < e1; e += 256) {
    int d = dst[e];
    int b = d >> NB_LOG;
    int r = atomicAdd(&lcnt[b], 1);
    ebuf[lspan[b] + r] =
        ((unsigned int)src[e] << NB_LOG) | (unsigned int)(d & NB_MASK);
  }
}

// ---------------------------------------------------------------------------
// K5: per-bucket aggregate into LDS + fused SAGE epilogue.
// Register-array staging forces 16 gathers in flight per lane (the round-3
// version compiled to VGPR=32 with ~1 outstanding load -> latency-bound).
// ---------------------------------------------------------------------------
__global__ __launch_bounds__(256) void agg_out_kernel(
    const float* __restrict__ h, const unsigned int* __restrict__ ebuf,
    const int* __restrict__ base,
    const float* __restrict__ wl, const float* __restrict__ bl,
    const float* __restrict__ wr, float* __restrict__ out, int n_nodes) {
  __shared__ float ssum[NB * 16];   // 4 KB
  __shared__ int   scnt[NB];
  __shared__ float swl[512];
  __shared__ float swr[512];
  __shared__ float sbl[32];

  int t = threadIdx.x;
  int b = blockIdx.x;

  for (int i = t; i < 512; i += 256) { swl[i] = wl[i]; swr[i] = wr[i]; }
  if (t < 32) sbl[t] = bl[t];
#pragma unroll
  for (int i = t; i < NB * 16; i += 256) ssum[i] = 0.0f;
  if (t < NB) scnt[t] = 0;
  __syncthreads();

  int beg = base[b];
  int end = base[b + 1];

  int g = t >> 4;        // 16 groups of 16 lanes
  int k = t & 15;

  int p = beg + g * 16;
  // full 16-edge chunks: stage all 16 gathers into registers (static
  // indices -> VGPRs, 16 loads in flight), then do the LDS adds.
  for (; p + 16 <= end; p += 256) {
    unsigned int ev = ebuf[p + k];
    unsigned int e2[16];
    float hv[16];
#pragma unroll
    for (int kk = 0; kk < 16; ++kk) {
      e2[kk] = __shfl(ev, kk, 16);
      hv[kk] = h[(size_t)(e2[kk] >> NB_LOG) * 16 + k];
    }
#pragma unroll
    for (int kk = 0; kk < 16; ++kk) {
      int dl = (int)(e2[kk] & NB_MASK);
      atomicAdd(&ssum[dl * 16 + k], hv[kk]);
      if (k == 0) atomicAdd(&scnt[dl], 1);
    }
  }
  // tail chunk (0 < m < 16), uniform within the group
  if (p < end) {
    int m = end - p;
    unsigned int ev = (k < m) ? ebuf[p + k] : 0u;
    for (int kk = 0; kk < m; ++kk) {
      unsigned int e2 = __shfl(ev, kk, 16);
      int s  = (int)(e2 >> NB_LOG);
      int dl = (int)(e2 & NB_MASK);
      atomicAdd(&ssum[dl * 16 + k], h[(size_t)s * 16 + k]);
      if (k == 0) atomicAdd(&scnt[dl], 1);
    }
  }
  __syncthreads();

  // epilogue: out = mean @ wl + bl + h @ wr for the 64 nodes of this bucket
  int j = t & 31;
  for (int nl = t >> 5; nl < NB; nl += 8) {
    int n = b * NB + nl;
    if (n >= n_nodes) break;
    float inv = 1.0f / fmaxf((float)scnt[nl], 1.0f);
    float acc = sbl[j];
    const float* hr = h + (size_t)n * 16;
#pragma unroll
    for (int kk = 0; kk < 16; ++kk) {
      float mv = ssum[nl * 16 + kk] * inv;
      acc += mv * swl[kk * 32 + j] + hr[kk] * swr[kk * 32 + j];
    }
    out[(size_t)n * 32 + j] = acc;
  }
}

// ---------------------------------------------------------------------------
// FALLBACK PATH (verified atomic kernels) — used only if ws too small or
// bucket table exceeds MAXBUCK.
// ---------------------------------------------------------------------------
__global__ __launch_bounds__(256) void scatter_kernel(
    const int* __restrict__ src, const int* __restrict__ dst,
    const float* __restrict__ h, float* __restrict__ summed,
    int* __restrict__ cnt, long long n_edges) {
  long long tid = (long long)blockIdx.x * blockDim.x + threadIdx.x;
  long long e = tid >> 4;
  int k = (int)(tid & 15);
  if (e >= n_edges) return;
  int s = src[e];
  int d = dst[e];
  float val = h[(size_t)s * 16 + k];
  atomicAdd(&summed[(size_t)d * 16 + k], val);
  if (k == 0) atomicAdd(&cnt[d], 1);
}

__global__ __launch_bounds__(256) void out_kernel(
    const float* __restrict__ h, const float* __restrict__ summed,
    const int* __restrict__ cnt,
    const float* __restrict__ wl, const float* __restrict__ bl,
    const float* __restrict__ wr, float* __restrict__ out, int n_nodes) {
  __shared__ float swl[512];
  __shared__ float swr[512];
  __shared__ float sbl[32];
  int t = threadIdx.x;
  for (int i = t; i < 512; i += 256) { swl[i] = wl[i]; swr[i] = wr[i]; }
  if (t < 32) sbl[t] = bl[t];
  __syncthreads();

  int gid = blockIdx.x * 256 + t;
  int n = gid >> 5;
  int j = gid & 31;
  if (n >= n_nodes) return;

  float inv = 1.0f / fmaxf((float)cnt[n], 1.0f);
  const float* hr = h + (size_t)n * 16;
  const float* sr = summed + (size_t)n * 16;
  float acc = sbl[j];
#pragma unroll
  for (int k = 0; k < 16; ++k) {
    acc += sr[k] * inv * swl[k * 32 + j] + hr[k] * swr[k * 32 + j];
  }
  out[(size_t)n * 32 + j] = acc;
}

// ---------------------------------------------------------------------------
extern "C" void kernel_launch(void* const* d_in, const int* in_sizes, int n_in,
                              void* d_out, int out_size, void* d_ws, size_t ws_size,
                              hipStream_t stream) {
  const float* x  = (const float*)d_in[0];
  const int* eidx = (const int*)d_in[1];
  const float* w1 = (const float*)d_in[2];
  const float* b1 = (const float*)d_in[3];
  const float* w2 = (const float*)d_in[4];
  const float* b2 = (const float*)d_in[5];
  const float* wl = (const float*)d_in[6];
  const float* bl = (const float*)d_in[7];
  const float* wr = (const float*)d_in[8];
  float* out = (float*)d_out;

  const int n_nodes = in_sizes[0] / D_IN_C;             // 100000
  const long long n_edges = (long long)in_sizes[1] / 2; // 3200000
  const int* src = eidx;
  const int* dst = eidx + n_edges;

  const int node_blocks = (n_nodes + 255) / 256;         // 391
  const int nbuck = (n_nodes + NB - 1) / NB;             // 1563
  const int epb_blocks = (int)((n_edges + EPB - 1) / EPB); // 250

  // New-path workspace layout.
  float*        h      = (float*)d_ws;                       // N*16 f32
  int*          gcount = (int*)(h + (size_t)n_nodes * 16);   // nbuck
  int*          cursor = gcount + nbuck;                     // nbuck
  int*          base   = cursor + nbuck;                     // nbuck+1
  unsigned int* ebuf   = (unsigned int*)(base + nbuck + 1);  // E u32

  size_t need = ((size_t)n_nodes * 16 + 3ull * nbuck + 1 + (size_t)n_edges) * 4;

  if (ws_size >= need && nbuck <= MAXBUCK) {
    // ---- coarse-bucket counting sort + LDS aggregation ----
    mlp_kernel<<<node_blocks, 256, 0, stream>>>(
        x, w1, b1, w2, b2, h, nullptr, nullptr, gcount, nbuck, n_nodes);
    hist_kernel<<<epb_blocks, 256, 0, stream>>>(dst, gcount, nbuck, (int)n_edges);
    scan_kernel<<<1, 256, 0, stream>>>(gcount, base, cursor, nbuck);
    bin_kernel<<<epb_blocks, 256, 0, stream>>>(src, dst, cursor, ebuf,
                                               nbuck, (int)n_edges);
    agg_out_kernel<<<nbuck, 256, 0, stream>>>(h, ebuf, base, wl, bl, wr, out,
                                              n_nodes);
  } else {
    // ---- fallback: verified atomic path ----
    float* summed = h + (size_t)n_nodes * 16;
    int*   fcnt   = (int*)(summed + (size_t)n_nodes * 16);
    mlp_kernel<<<node_blocks, 256, 0, stream>>>(
        x, w1, b1, w2, b2, h, summed, fcnt, nullptr, 0, n_nodes);
    {
      long long total = n_edges * 16;
      int blocks = (int)((total + 255) / 256);
      scatter_kernel<<<blocks, 256, 0, stream>>>(src, dst, h, summed, fcnt, n_edges);
    }
    {
      long long total = (long long)n_nodes * 32;
      int blocks = (int)((total + 255) / 256);
      out_kernel<<<blocks, 256, 0, stream>>>(h, summed, fcnt, wl, bl, wr, out, n_nodes);
    }
  }
}

// Round 5
// 452.323 us; speedup vs baseline: 1.6679x; 1.1440x over previous
//
#include <hip/hip_runtime.h>

#define D_IN_C 16
#define D_OUT_C 32
#define NB_LOG 6                 // 64 nodes per bucket
#define NB (1 << NB_LOG)         // 64
#define NB_MASK (NB - 1)
#define MAXBUCK 1600             // supports up to 102400 nodes
#define EPB 12800                // edges per block in hist/bin

// ---------------------------------------------------------------------------
// K1: h = relu(x@w1+b1)@w2+b2 ; zero bucket counts (new path) or
// summed/cnt (fallback path).
// ---------------------------------------------------------------------------
__global__ __launch_bounds__(256) void mlp_kernel(
    const float* __restrict__ x,
    const float* __restrict__ w1, const float* __restrict__ b1,
    const float* __restrict__ w2, const float* __restrict__ b2,
    float* __restrict__ h, float* __restrict__ summed, int* __restrict__ cnt,
    int* __restrict__ gcount, int nbuck, int n_nodes) {
  __shared__ float sw1[256];
  __shared__ float sw2[256];
  __shared__ float sb1[16];
  __shared__ float sb2[16];
  int t = threadIdx.x;
  sw1[t] = w1[t];
  sw2[t] = w2[t];
  if (t < 16) { sb1[t] = b1[t]; sb2[t] = b2[t]; }
  __syncthreads();

  int n = blockIdx.x * blockDim.x + t;

  if (gcount && n < nbuck) gcount[n] = 0;
  if (n >= n_nodes) return;

  float xi[16];
  const float4* xr = (const float4*)(x + (size_t)n * 16);
  float4 v0 = xr[0], v1 = xr[1], v2 = xr[2], v3 = xr[3];
  xi[0]=v0.x; xi[1]=v0.y; xi[2]=v0.z; xi[3]=v0.w;
  xi[4]=v1.x; xi[5]=v1.y; xi[6]=v1.z; xi[7]=v1.w;
  xi[8]=v2.x; xi[9]=v2.y; xi[10]=v2.z; xi[11]=v2.w;
  xi[12]=v3.x; xi[13]=v3.y; xi[14]=v3.z; xi[15]=v3.w;

  float t1[16];
#pragma unroll
  for (int j = 0; j < 16; ++j) {
    float acc = sb1[j];
#pragma unroll
    for (int k = 0; k < 16; ++k) acc += xi[k] * sw1[k * 16 + j];
    t1[j] = fmaxf(acc, 0.0f);
  }
  float hh[16];
#pragma unroll
  for (int j = 0; j < 16; ++j) {
    float acc = sb2[j];
#pragma unroll
    for (int k = 0; k < 16; ++k) acc += t1[k] * sw2[k * 16 + j];
    hh[j] = acc;
  }

  float4* hw = (float4*)(h + (size_t)n * 16);
  hw[0] = make_float4(hh[0], hh[1], hh[2], hh[3]);
  hw[1] = make_float4(hh[4], hh[5], hh[6], hh[7]);
  hw[2] = make_float4(hh[8], hh[9], hh[10], hh[11]);
  hw[3] = make_float4(hh[12], hh[13], hh[14], hh[15]);

  if (cnt) cnt[n] = 0;
  if (summed) {
    float4* sz = (float4*)(summed + (size_t)n * 16);
    float4 z = make_float4(0.f, 0.f, 0.f, 0.f);
    sz[0] = z; sz[1] = z; sz[2] = z; sz[3] = z;
  }
}

// ---------------------------------------------------------------------------
// K2: per-bucket histogram, LDS-aggregated per block. 1024 threads for
// latency hiding (16 waves/CU at 1 block/CU).
// ---------------------------------------------------------------------------
__global__ __launch_bounds__(1024) void hist_kernel(
    const int* __restrict__ dst, int* __restrict__ gcount,
    int nbuck, int n_edges) {
  __shared__ int lcnt[MAXBUCK];
  int t = threadIdx.x;
  for (int i = t; i < MAXBUCK; i += 1024) lcnt[i] = 0;
  __syncthreads();
  int e0 = blockIdx.x * EPB;
  int e1 = e0 + EPB; if (e1 > n_edges) e1 = n_edges;
  for (int e = e0 + t; e < e1; e += 1024)
    atomicAdd(&lcnt[dst[e] >> NB_LOG], 1);
  __syncthreads();
  for (int b = t; b < nbuck; b += 1024) {
    int c = lcnt[b];
    if (c) atomicAdd(&gcount[b], c);
  }
}

// ---------------------------------------------------------------------------
// K3: single-block exclusive scan over nbuck bucket counts.
// ---------------------------------------------------------------------------
__global__ __launch_bounds__(256) void scan_kernel(
    const int* __restrict__ gcount, int* __restrict__ base,
    int* __restrict__ cursor, int nbuck) {
  __shared__ int ps[256];
  int t = threadIdx.x;
  int per = (nbuck + 255) / 256;
  int beg = t * per;
  int end = beg + per; if (end > nbuck) end = nbuck;
  int sum = 0;
  for (int i = beg; i < end; ++i) sum += gcount[i];
  ps[t] = sum;
  __syncthreads();
#pragma unroll
  for (int off = 1; off < 256; off <<= 1) {
    int add = (t >= off) ? ps[t - off] : 0;
    __syncthreads();
    ps[t] += add;
    __syncthreads();
  }
  int run = ps[t] - sum;  // exclusive prefix
  for (int i = beg; i < end; ++i) {
    base[i] = run;
    cursor[i] = run;
    run += gcount[i];
  }
  if (t == 255) base[nbuck] = ps[255];
}

// ---------------------------------------------------------------------------
// K4: bin edges. Per block: LDS count -> span reservation -> LDS-rank
// scatter. pack = (src << 6) | (dst & 63)
// ---------------------------------------------------------------------------
__global__ __launch_bounds__(1024) void bin_kernel(
    const int* __restrict__ src, const int* __restrict__ dst,
    int* __restrict__ cursor, unsigned int* __restrict__ ebuf,
    int nbuck, int n_edges) {
  __shared__ int lcnt[MAXBUCK];
  __shared__ int lspan[MAXBUCK];
  int t = threadIdx.x;
  for (int i = t; i < MAXBUCK; i += 1024) lcnt[i] = 0;
  __syncthreads();
  int e0 = blockIdx.x * EPB;
  int e1 = e0 + EPB; if (e1 > n_edges) e1 = n_edges;
  // phase A: local count
  for (int e = e0 + t; e < e1; e += 1024)
    atomicAdd(&lcnt[dst[e] >> NB_LOG], 1);
  __syncthreads();
  // phase B: reserve spans, reset counters for rank pass
  for (int b = t; b < nbuck; b += 1024) {
    int c = lcnt[b];
    lspan[b] = c ? atomicAdd(&cursor[b], c) : 0;
    lcnt[b] = 0;
  }
  __syncthreads();
  // phase C: scatter
  for (int e = e0 + t; e < e1; e += 1024) {
    int d = dst[e];
    int b = d >> NB_LOG;
    int r = atomicAdd(&lcnt[b], 1);
    ebuf[lspan[b] + r] =
        ((unsigned int)src[e] << NB_LOG) | (unsigned int)(d & NB_MASK);
  }
}

// ---------------------------------------------------------------------------
// K5: per-bucket aggregate into LDS + fused SAGE epilogue.
// ROW-PER-LANE gather: one edge per thread; 16 independent scalar loads of
// the edge's full 64B h-row (lane-rotated order so LDS banks spread while
// register indices stay static). NO shfl in the gather loop — the round-4
// version's ds_bpermute shared lgkmcnt with the LDS atomics, serializing
// the global loads to ~1 in flight (measured 333 GB/s == occupancy * 1
// line / 600ns). One wave-instruction now requests up to 64 distinct lines.
// ---------------------------------------------------------------------------
__global__ __launch_bounds__(256) void agg_out_kernel(
    const float* __restrict__ h, const unsigned int* __restrict__ ebuf,
    const int* __restrict__ base,
    const float* __restrict__ wl, const float* __restrict__ bl,
    const float* __restrict__ wr, float* __restrict__ out, int n_nodes) {
  __shared__ float ssum[NB * 16];   // 4 KB
  __shared__ int   scnt[NB];
  __shared__ float swl[512];
  __shared__ float swr[512];
  __shared__ float sbl[32];

  int t = threadIdx.x;
  int b = blockIdx.x;

  for (int i = t; i < 512; i += 256) { swl[i] = wl[i]; swr[i] = wr[i]; }
  if (t < 32) sbl[t] = bl[t];
#pragma unroll
  for (int i = t; i < NB * 16; i += 256) ssum[i] = 0.0f;
  if (t < NB) scnt[t] = 0;
  __syncthreads();

  int beg = base[b];
  int end = base[b + 1];
  int rot = t & 15;

  for (int p = beg + t; p < end; p += 256) {
    unsigned int e2 = ebuf[p];                 // coalesced
    int s  = (int)(e2 >> NB_LOG);
    int dl = (int)(e2 & NB_MASK);
    const float* hr = h + (size_t)s * 16;
    float v[16];
#pragma unroll
    for (int j = 0; j < 16; ++j)               // 16 independent loads,
      v[j] = hr[(rot + j) & 15];               // all issued before use
#pragma unroll
    for (int j = 0; j < 16; ++j)
      atomicAdd(&ssum[dl * 16 + ((rot + j) & 15)], v[j]);
    atomicAdd(&scnt[dl], 1);
  }
  __syncthreads();

  // epilogue: out = mean @ wl + bl + h @ wr for the 64 nodes of this bucket
  int j = t & 31;
  for (int nl = t >> 5; nl < NB; nl += 8) {
    int n = b * NB + nl;
    if (n >= n_nodes) break;
    float inv = 1.0f / fmaxf((float)scnt[nl], 1.0f);
    float acc = sbl[j];
    const float* hr = h + (size_t)n * 16;
#pragma unroll
    for (int kk = 0; kk < 16; ++kk) {
      float mv = ssum[nl * 16 + kk] * inv;
      acc += mv * swl[kk * 32 + j] + hr[kk] * swr[kk * 32 + j];
    }
    out[(size_t)n * 32 + j] = acc;
  }
}

// ---------------------------------------------------------------------------
// FALLBACK PATH (verified atomic kernels) — used only if ws too small or
// bucket table exceeds MAXBUCK.
// ---------------------------------------------------------------------------
__global__ __launch_bounds__(256) void scatter_kernel(
    const int* __restrict__ src, const int* __restrict__ dst,
    const float* __restrict__ h, float* __restrict__ summed,
    int* __restrict__ cnt, long long n_edges) {
  long long tid = (long long)blockIdx.x * blockDim.x + threadIdx.x;
  long long e = tid >> 4;
  int k = (int)(tid & 15);
  if (e >= n_edges) return;
  int s = src[e];
  int d = dst[e];
  float val = h[(size_t)s * 16 + k];
  atomicAdd(&summed[(size_t)d * 16 + k], val);
  if (k == 0) atomicAdd(&cnt[d], 1);
}

__global__ __launch_bounds__(256) void out_kernel(
    const float* __restrict__ h, const float* __restrict__ summed,
    const int* __restrict__ cnt,
    const float* __restrict__ wl, const float* __restrict__ bl,
    const float* __restrict__ wr, float* __restrict__ out, int n_nodes) {
  __shared__ float swl[512];
  __shared__ float swr[512];
  __shared__ float sbl[32];
  int t = threadIdx.x;
  for (int i = t; i < 512; i += 256) { swl[i] = wl[i]; swr[i] = wr[i]; }
  if (t < 32) sbl[t] = bl[t];
  __syncthreads();

  int gid = blockIdx.x * 256 + t;
  int n = gid >> 5;
  int j = gid & 31;
  if (n >= n_nodes) return;

  float inv = 1.0f / fmaxf((float)cnt[n], 1.0f);
  const float* hr = h + (size_t)n * 16;
  const float* sr = summed + (size_t)n * 16;
  float acc = sbl[j];
#pragma unroll
  for (int k = 0; k < 16; ++k) {
    acc += sr[k] * inv * swl[k * 32 + j] + hr[k] * swr[k * 32 + j];
  }
  out[(size_t)n * 32 + j] = acc;
}

// ---------------------------------------------------------------------------
extern "C" void kernel_launch(void* const* d_in, const int* in_sizes, int n_in,
                              void* d_out, int out_size, void* d_ws, size_t ws_size,
                              hipStream_t stream) {
  const float* x  = (const float*)d_in[0];
  const int* eidx = (const int*)d_in[1];
  const float* w1 = (const float*)d_in[2];
  const float* b1 = (const float*)d_in[3];
  const float* w2 = (const float*)d_in[4];
  const float* b2 = (const float*)d_in[5];
  const float* wl = (const float*)d_in[6];
  const float* bl = (const float*)d_in[7];
  const float* wr = (const float*)d_in[8];
  float* out = (float*)d_out;

  const int n_nodes = in_sizes[0] / D_IN_C;             // 100000
  const long long n_edges = (long long)in_sizes[1] / 2; // 3200000
  const int* src = eidx;
  const int* dst = eidx + n_edges;

  const int node_blocks = (n_nodes + 255) / 256;         // 391
  const int nbuck = (n_nodes + NB - 1) / NB;             // 1563
  const int epb_blocks = (int)((n_edges + EPB - 1) / EPB); // 250

  // New-path workspace layout.
  float*        h      = (float*)d_ws;                       // N*16 f32
  int*          gcount = (int*)(h + (size_t)n_nodes * 16);   // nbuck
  int*          cursor = gcount + nbuck;                     // nbuck
  int*          base   = cursor + nbuck;                     // nbuck+1
  unsigned int* ebuf   = (unsigned int*)(base + nbuck + 1);  // E u32

  size_t need = ((size_t)n_nodes * 16 + 3ull * nbuck + 1 + (size_t)n_edges) * 4;

  if (ws_size >= need && nbuck <= MAXBUCK) {
    // ---- coarse-bucket counting sort + LDS aggregation ----
    mlp_kernel<<<node_blocks, 256, 0, stream>>>(
        x, w1, b1, w2, b2, h, nullptr, nullptr, gcount, nbuck, n_nodes);
    hist_kernel<<<epb_blocks, 1024, 0, stream>>>(dst, gcount, nbuck, (int)n_edges);
    scan_kernel<<<1, 256, 0, stream>>>(gcount, base, cursor, nbuck);
    bin_kernel<<<epb_blocks, 1024, 0, stream>>>(src, dst, cursor, ebuf,
                                                nbuck, (int)n_edges);
    agg_out_kernel<<<nbuck, 256, 0, stream>>>(h, ebuf, base, wl, bl, wr, out,
                                              n_nodes);
  } else {
    // ---- fallback: verified atomic path ----
    float* summed = h + (size_t)n_nodes * 16;
    int*   fcnt   = (int*)(summed + (size_t)n_nodes * 16);
    mlp_kernel<<<node_blocks, 256, 0, stream>>>(
        x, w1, b1, w2, b2, h, summed, fcnt, nullptr, 0, n_nodes);
    {
      long long total = n_edges * 16;
      int blocks = (int)((total + 255) / 256);
      scatter_kernel<<<blocks, 256, 0, stream>>>(src, dst, h, summed, fcnt, n_edges);
    }
    {
      long long total = (long long)n_nodes * 32;
      int blocks = (int)((total + 255) / 256);
      out_kernel<<<blocks, 256, 0, stream>>>(h, summed, fcnt, wl, bl, wr, out, n_nodes);
    }
  }
}